// Round 7
// baseline (110.001 us; speedup 1.0000x reference)
//
#include <hip/hip_runtime.h>
#include <math.h>

#define NQ   10
#define NLAY 4
#define BATCH 4096
#define HID  32
#define NM   20   // 2*NQ

typedef float    f2  __attribute__((ext_vector_type(2)));
typedef unsigned u2v __attribute__((ext_vector_type(2)));

// ---------------------------------------------------------------------------
// Compile-time tracking of the CNOT ring as a GF(2) linear map.
// col[l][k] = pair-xor mask between storage indices for layer-l gate on wire k
// row[l][k] = parity mask giving logical bit x_k from storage index
// ---------------------------------------------------------------------------
struct Tables {
    unsigned col[NLAY + 1][NQ];
    unsigned row[NLAY + 1][NQ];
};

constexpr Tables make_tables() {
    Tables t{};
    unsigned col[NQ] = {}, row[NQ] = {};
    for (int k = 0; k < NQ; ++k) { col[k] = 1u << (NQ - 1 - k); row[k] = 1u << (NQ - 1 - k); }
    for (int l = 0; l <= NLAY; ++l) {
        for (int k = 0; k < NQ; ++k) { t.col[l][k] = col[k]; t.row[l][k] = row[k]; }
        for (int k = 0; k < NQ; ++k) {            // ring: CNOT(k, (k+1)%NQ)
            int c = k, tg = (k + 1) % NQ;
            col[c] ^= col[tg];
            row[tg] ^= row[c];
        }
    }
    return t;
}

static constexpr Tables TB = make_tables();

struct cpx { float x, y; };
__device__ __forceinline__ cpx cxmul(cpx a, cpx b) {
    return { fmaf(a.x, b.x, -a.y * b.y), fmaf(a.x, b.y, a.y * b.x) };
}

__device__ __forceinline__ f2 mk2(float a, float b) { f2 r; r[0] = a; r[1] = b; return r; }
__device__ __forceinline__ f2 ffma(f2 a, f2 b, f2 c) { return __builtin_elementwise_fma(a, b, c); }

// acc += a (*) b   complex, interleaved (re,im) per f2.
__device__ __forceinline__ f2 cmac(f2 acc, f2 a, f2 b) {
    acc = ffma(mk2(a[0], a[0]), b, acc);
    acc = ffma(mk2(-a[1], a[1]), mk2(b[1], b[0]), acc);
    return acc;
}

// ---- mov_dpp lane-xor within a 16-lane row (1 VALU inst, no tied old) -----
template<int CTRL>
__device__ __forceinline__ float movdpp(float x) {
    return __int_as_float(__builtin_amdgcn_mov_dpp(
        __float_as_int(x), CTRL, 0xF, 0xF, true));
}

template<unsigned M>
__device__ __forceinline__ float dpplo(float x) {
    static_assert(M < 16u, "dpplo handles masks 0..15");
    if constexpr (M == 0u)       return x;
    else if constexpr (M == 1u)  return movdpp<0xB1>(x);                  // quad_perm [1,0,3,2]
    else if constexpr (M == 2u)  return movdpp<0x4E>(x);                  // quad_perm [2,3,0,1]
    else if constexpr (M == 3u)  return movdpp<0x1B>(x);                  // quad_perm [3,2,1,0]
    else if constexpr (M == 7u)  return movdpp<0x141>(x);                 // row_half_mirror
    else if constexpr (M == 8u)  return movdpp<0x128>(x);                 // row_ror:8
    else if constexpr (M == 15u) return movdpp<0x140>(x);                 // row_mirror
    else if constexpr (M == 4u)  return movdpp<0x141>(movdpp<0x1B>(x));   // 7^3
    else if constexpr (M == 5u)  return movdpp<0x141>(movdpp<0x4E>(x));   // 7^2
    else if constexpr (M == 6u)  return movdpp<0x141>(movdpp<0xB1>(x));   // 7^1
    else if constexpr (M == 9u)  return movdpp<0x128>(movdpp<0xB1>(x));   // 8^1
    else if constexpr (M == 10u) return movdpp<0x128>(movdpp<0x4E>(x));   // 8^2
    else if constexpr (M == 11u) return movdpp<0x128>(movdpp<0x1B>(x));   // 8^3
    else if constexpr (M == 12u) return movdpp<0x140>(movdpp<0x1B>(x));   // 15^3
    else if constexpr (M == 13u) return movdpp<0x140>(movdpp<0x4E>(x));   // 15^2
    else                         return movdpp<0x140>(movdpp<0xB1>(x));   // 14 = 15^1
}

// ---- gfx950 permlane row swaps: xor-16 / xor-32 on the VALU pipe ----------
// Probed convention: sel is a per-lane bool such that (sel ? r[0] : r[1]) == x[lane^16].
__device__ __forceinline__ float swap16sel(float x, bool sel16) {
#if __has_builtin(__builtin_amdgcn_permlane16_swap)
    u2v r = __builtin_amdgcn_permlane16_swap(__float_as_uint(x), __float_as_uint(x), false, false);
    return sel16 ? __uint_as_float(r[0]) : __uint_as_float(r[1]);
#else
    (void)sel16; return __shfl_xor(x, 16);
#endif
}
__device__ __forceinline__ float swap32sel(float x, bool sel32) {
#if __has_builtin(__builtin_amdgcn_permlane32_swap)
    u2v r = __builtin_amdgcn_permlane32_swap(__float_as_uint(x), __float_as_uint(x), false, false);
    return sel32 ? __uint_as_float(r[0]) : __uint_as_float(r[1]);
#else
    (void)sel32; return __shfl_xor(x, 32);
#endif
}
__device__ __forceinline__ float redfold16(float x) {
#if __has_builtin(__builtin_amdgcn_permlane16_swap)
    u2v r = __builtin_amdgcn_permlane16_swap(__float_as_uint(x), __float_as_uint(x), false, false);
    return __uint_as_float(r[0]) + __uint_as_float(r[1]);
#else
    return x + __shfl_xor(x, 16);
#endif
}
__device__ __forceinline__ float redfold32(float x) {
#if __has_builtin(__builtin_amdgcn_permlane32_swap)
    u2v r = __builtin_amdgcn_permlane32_swap(__float_as_uint(x), __float_as_uint(x), false, false);
    return __uint_as_float(r[0]) + __uint_as_float(r[1]);
#else
    return x + __shfl_xor(x, 32);
#endif
}

// lane-xor by compile-time MASK — all on the VALU pipe (no DS in gate loop).
template<unsigned M>
__device__ __forceinline__ float xlane(float x, bool sel16, bool sel32) {
    float y = dpplo<M & 15u>(x);
    if constexpr ((M & 16u) != 0u) y = swap16sel(y, sel16);
    if constexpr ((M & 32u) != 0u) y = swap32sel(y, sel32);
    return y;
}

// ---- one single-qubit gate, interleaved-complex state, fully specialized --
template<int L, int K>
__device__ __forceinline__ void apply_gate(f2 (&st)[16],
                                           const float4 (*gm)[2], const int lane,
                                           const bool sel16, const bool sel32) {
    constexpr unsigned v  = TB.col[L][K];
    constexpr unsigned m  = TB.row[L][K];
    constexpr unsigned vl = v >> 4;
    constexpr int      vr = (int)(v & 15u);
    constexpr unsigned ml = m >> 4;
    constexpr int      mr = (int)(m & 15u);
    constexpr int      gi = L * NQ + K;

    int laneP = 0;
    if constexpr (ml != 0) laneP = __popc((unsigned)lane & ml) & 1;
    const float4 A = gm[gi][laneP];
    const f2 ocA = mk2(A.x, A.y), pcA = mk2(A.z, A.w);
    f2 ocB = ocA, pcB = pcA;
    if constexpr (mr != 0) {
        const float4 B = gm[gi][laneP ^ 1];
        ocB = mk2(B.x, B.y); pcB = mk2(B.z, B.w);
    }

    // partner values (all read before any write)
    f2 pv[16];
    #pragma unroll
    for (int r = 0; r < 16; ++r) {
        const f2 q = st[r ^ vr];
        if constexpr (vl == 0u) pv[r] = q;
        else pv[r] = mk2(xlane<vl>(q[0], sel16, sel32), xlane<vl>(q[1], sel16, sel32));
    }
    #pragma unroll
    for (int r = 0; r < 16; ++r) {
        const int pr = __builtin_popcount((unsigned)(r & mr)) & 1;  // compile-time folds
        const f2 oc = pr ? ocB : ocA;
        const f2 pc = pr ? pcB : pcA;
        f2 acc = mk2(0.f, 0.f);
        acc = cmac(acc, oc, st[r]);
        acc = cmac(acc, pc, pv[r]);
        st[r] = acc;
    }
}

__global__ __launch_bounds__(256, 4) void qrh_kernel(
    const float* __restrict__ theta, const float* __restrict__ rotw,
    const float* __restrict__ escale, const float* __restrict__ ebias,
    const float* __restrict__ W1, const float* __restrict__ b1,
    const float* __restrict__ W2, const float* __restrict__ b2,
    float* __restrict__ out)
{
    // per gate: group0 = [U00.re,U00.im,U01.re,U01.im], group1 = [U11.re,U11.im,U10.re,U10.im]
    __shared__ float4 gmat[4][NLAY * NQ][2];
    __shared__ float4 wtab[4][NQ];   // layer-0 product vectors: (a.re,a.im,b.re,b.im)

    const int tid  = threadIdx.x;
    const int lane = tid & 63;
    const int wv   = tid >> 6;
    const int b    = blockIdx.x * 4 + wv;

    // probe permlane swap convention once: sel ? r[0] : r[1]  ==  x[lane^16/32]
    bool sel16 = false, sel32 = false;
#if __has_builtin(__builtin_amdgcn_permlane16_swap)
    {
        u2v r = __builtin_amdgcn_permlane16_swap((unsigned)lane, (unsigned)lane, false, false);
        sel16 = (r[0] == (unsigned)(lane ^ 16));
    }
#endif
#if __has_builtin(__builtin_amdgcn_permlane32_swap)
    {
        u2v r = __builtin_amdgcn_permlane32_swap((unsigned)lane, (unsigned)lane, false, false);
        sel32 = (r[0] == (unsigned)(lane ^ 32));
    }
#endif

    // ---- per-gate 2x2 unitary, lane-parallel (lanes 0..39) ----
    if (lane < NLAY * NQ) {
        const int g = lane, l = g / NQ, k = g % NQ;
        const float th = theta[b * NQ + k];
        const int e2 = (l * NQ + k) * 2;
        const float t0 = escale[e2 + 0] * th + ebias[e2 + 0];
        const float t1 = escale[e2 + 1] * th + ebias[e2 + 1];
        float sn0, c0, sn1, c1;
        __sincosf(0.5f * t0, &sn0, &c0);
        __sincosf(0.5f * t1, &sn1, &c1);
        // U_enc = RX(t1) RZ(t0)
        const f2 E00 = mk2( c1 * c0,  -c1 * sn0);
        const f2 E01 = mk2( sn1 * sn0, -sn1 * c0);
        const f2 E10 = mk2(-sn1 * sn0, -sn1 * c0);
        const f2 E11 = mk2( c1 * c0,   c1 * sn0);
        const int r3 = (l * NQ + k) * 3;
        const float w0 = rotw[r3 + 0], w1 = rotw[r3 + 1], w2 = rotw[r3 + 2];
        float cw, sw, ca0, sa0, ca1, sa1;
        __sincosf(0.5f * w1, &sw, &cw);
        __sincosf(0.5f * (w0 + w2), &sa0, &ca0);
        __sincosf(0.5f * (w0 - w2), &sa1, &ca1);
        // U_rot = RZ(w2) RY(w1) RZ(w0)
        const f2 R00 = mk2( cw * ca0, -cw * sa0);
        const f2 R01 = mk2(-sw * ca1, -sw * sa1);
        const f2 R10 = mk2( sw * ca1, -sw * sa1);
        const f2 R11 = mk2( cw * ca0,  cw * sa0);
        auto cm = [](f2 a, f2 bb) { return mk2(a[0]*bb[0] - a[1]*bb[1], a[0]*bb[1] + a[1]*bb[0]); };
        const f2 U00 = cm(R00, E00) + cm(R01, E10);
        const f2 U01 = cm(R00, E01) + cm(R01, E11);
        const f2 U10 = cm(R10, E00) + cm(R11, E10);
        const f2 U11 = cm(R10, E01) + cm(R11, E11);
        gmat[wv][g][0] = make_float4(U00[0], U00[1], U01[0], U01[1]);
        gmat[wv][g][1] = make_float4(U11[0], U11[1], U10[0], U10[1]);
        if (l == 0) {
            // layer-0 acts on |+>^10: per-wire 2-vector w = U*(1,1)/sqrt(2)
            const float inv = 0.70710678118654752f;
            const f2 al = (U00 + U01) * inv;
            const f2 be = (U10 + U11) * inv;
            wtab[wv][k] = make_float4(al[0], al[1], be[0], be[1]);
        }
    }
    __syncthreads();

    // ---- layer-0 state = product state: amp(s) = prod_k w_k[s_k] ----------
    // storage s = (lane<<4) | r ; wires 0..5 <-> lane bits 5..0; wires 6..9 <-> r bits 3..0
    f2 st[16];
    {
        cpx pre;
        {
            const float4 q = wtab[wv][0];
            pre = ((lane >> 5) & 1) ? cpx{q.z, q.w} : cpx{q.x, q.y};
            #pragma unroll
            for (int k = 1; k < 6; ++k) {
                const float4 t = wtab[wv][k];
                const cpx w_ = ((lane >> (5 - k)) & 1) ? cpx{t.z, t.w} : cpx{t.x, t.y};
                pre = cxmul(pre, w_);
            }
        }
        const float4 q6 = wtab[wv][6], q7 = wtab[wv][7];
        const float4 q8 = wtab[wv][8], q9 = wtab[wv][9];
        const cpx w6[2] = {{q6.x, q6.y}, {q6.z, q6.w}};
        const cpx w7[2] = {{q7.x, q7.y}, {q7.z, q7.w}};
        const cpx w8[2] = {{q8.x, q8.y}, {q8.z, q8.w}};
        const cpx w9[2] = {{q9.x, q9.y}, {q9.z, q9.w}};
        cpx ph[4], tlo[4];
        #pragma unroll
        for (int a = 0; a < 4; ++a) {
            ph[a]  = cxmul(pre, cxmul(w6[a >> 1], w7[a & 1]));
            tlo[a] = cxmul(w8[a >> 1], w9[a & 1]);
        }
        #pragma unroll
        for (int r = 0; r < 16; ++r) {
            const cpx a0 = cxmul(ph[r >> 2], tlo[r & 3]);
            st[r] = mk2(a0.x, a0.y);
        }
    }

    const float4 (*gm)[2] = gmat[wv];

    #define GATE(L,K) apply_gate<L,K>(st, gm, lane, sel16, sel32);
    #define LAYER(L) GATE(L,0) GATE(L,1) GATE(L,2) GATE(L,3) GATE(L,4) \
                     GATE(L,5) GATE(L,6) GATE(L,7) GATE(L,8) GATE(L,9)
    LAYER(1)
    LAYER(2)
    LAYER(3)
    #undef LAYER
    #undef GATE

    // ---- measurement: probs then 4-bit FWHT over register index ----
    float w[16];
    #pragma unroll
    for (int r = 0; r < 16; ++r) {
        const f2 sq = st[r] * st[r];
        w[r] = sq[0] + sq[1];
    }
    #pragma unroll
    for (int bit = 1; bit < 16; bit <<= 1) {
        #pragma unroll
        for (int j = 0; j < 16; ++j) {
            if (!(j & bit)) {
                const float a = w[j], c = w[j | bit];
                w[j] = a + c; w[j | bit] = a - c;
            }
        }
    }
    // w[t] = sum_j (-1)^{popc(j&t)} p[j]

    float feats[NM];
    #pragma unroll
    for (int f = 0; f < NM; ++f) {
        const unsigned M = (f < NQ) ? TB.row[NLAY][f]
                                    : (TB.row[NLAY][f - NQ] ^ TB.row[NLAY][(f - NQ + 1) % NQ]);
        const int Ml = (int)(M >> 4), Mj = (int)(M & 15u);
        const float s = w[Mj];
        const int lsgn = __popc((unsigned)lane & (unsigned)Ml) & 1;
        feats[f] = lsgn ? -s : s;
    }
    // wave reduction over basis masks {1,2,7,8,16,32} (all VALU)
    #pragma unroll
    for (int f = 0; f < NM; ++f) {
        float v = feats[f];
        v += movdpp<0xB1>(v);    // ^1
        v += movdpp<0x4E>(v);    // ^2
        v += movdpp<0x141>(v);   // ^7
        v += movdpp<0x128>(v);   // ^8
        v = redfold16(v);
        v = redfold32(v);
        feats[f] = v;
    }

    // ---- MLP head: lanes 0..31 each one hidden unit ----
    float part = 0.f;
    if (lane < HID) {
        float acc = b1[lane];
        #pragma unroll
        for (int mm = 0; mm < NM; ++mm) acc = fmaf(feats[mm], W1[lane * NM + mm], acc);
        const float sg = 1.f / (1.f + __expf(-acc));
        part = acc * sg * W2[lane];
    }
    part += movdpp<0xB1>(part);
    part += movdpp<0x4E>(part);
    part += movdpp<0x141>(part);
    part += movdpp<0x128>(part);
    part = redfold16(part);
    part = redfold32(part);
    if (lane == 0) out[b] = part + b2[0];
}

extern "C" void kernel_launch(void* const* d_in, const int* in_sizes, int n_in,
                              void* d_out, int out_size, void* d_ws, size_t ws_size,
                              hipStream_t stream) {
    (void)in_sizes; (void)n_in; (void)out_size; (void)d_ws; (void)ws_size;
    const float* theta = (const float*)d_in[0];
    const float* rotw  = (const float*)d_in[1];
    const float* esc   = (const float*)d_in[2];
    const float* ebi   = (const float*)d_in[3];
    const float* W1    = (const float*)d_in[4];
    const float* b1    = (const float*)d_in[5];
    const float* W2    = (const float*)d_in[6];
    const float* b2    = (const float*)d_in[7];
    float* out = (float*)d_out;

    qrh_kernel<<<BATCH / 4, 256, 0, stream>>>(theta, rotw, esc, ebi, W1, b1, W2, b2, out);
}

// Round 8
// 96.867 us; speedup vs baseline: 1.1356x; 1.1356x over previous
//
#include <hip/hip_runtime.h>
#include <math.h>

#define NQ   10
#define NLAY 4
#define BATCH 4096
#define HID  32
#define NM   20   // 2*NQ

typedef float    f2  __attribute__((ext_vector_type(2)));
typedef unsigned u2v __attribute__((ext_vector_type(2)));

// ---------------------------------------------------------------------------
// Compile-time tracking of the CNOT ring as a GF(2) linear map.
// col[l][k] = pair-xor mask between storage indices for layer-l gate on wire k
// row[l][k] = parity mask giving logical bit x_k from storage index
// ---------------------------------------------------------------------------
struct Tables {
    unsigned col[NLAY + 1][NQ];
    unsigned row[NLAY + 1][NQ];
};

constexpr Tables make_tables() {
    Tables t{};
    unsigned col[NQ] = {}, row[NQ] = {};
    for (int k = 0; k < NQ; ++k) { col[k] = 1u << (NQ - 1 - k); row[k] = 1u << (NQ - 1 - k); }
    for (int l = 0; l <= NLAY; ++l) {
        for (int k = 0; k < NQ; ++k) { t.col[l][k] = col[k]; t.row[l][k] = row[k]; }
        for (int k = 0; k < NQ; ++k) {            // ring: CNOT(k, (k+1)%NQ)
            int c = k, tg = (k + 1) % NQ;
            col[c] ^= col[tg];
            row[tg] ^= row[c];
        }
    }
    return t;
}

static constexpr Tables TB = make_tables();

struct cpx { float x, y; };
__device__ __forceinline__ cpx cxmul(cpx a, cpx b) {
    return { fmaf(a.x, b.x, -a.y * b.y), fmaf(a.x, b.y, a.y * b.x) };
}

__device__ __forceinline__ f2 mk2(float a, float b) { f2 r; r[0] = a; r[1] = b; return r; }
__device__ __forceinline__ f2 ffma(f2 a, f2 b, f2 c) { return __builtin_elementwise_fma(a, b, c); }

// acc += a (*) b   complex, interleaved (re,im) per f2.
__device__ __forceinline__ f2 cmac(f2 acc, f2 a, f2 b) {
    acc = ffma(mk2(a[0], a[0]), b, acc);
    acc = ffma(mk2(-a[1], a[1]), mk2(b[1], b[0]), acc);
    return acc;
}

// ---- DPP lane-xor within a 16-lane row (VALU pipe) ------------------------
template<int CTRL>
__device__ __forceinline__ float dppf(float x) {
    return __int_as_float(__builtin_amdgcn_update_dpp(
        0, __float_as_int(x), CTRL, 0xF, 0xF, true));
}

template<unsigned M>
__device__ __forceinline__ float dpplo(float x) {
    static_assert(M < 16u, "dpplo handles masks 0..15");
    if constexpr (M == 0u)       return x;
    else if constexpr (M == 1u)  return dppf<0xB1>(x);                 // quad_perm [1,0,3,2]
    else if constexpr (M == 2u)  return dppf<0x4E>(x);                 // quad_perm [2,3,0,1]
    else if constexpr (M == 3u)  return dppf<0x1B>(x);                 // quad_perm [3,2,1,0]
    else if constexpr (M == 7u)  return dppf<0x141>(x);                // row_half_mirror
    else if constexpr (M == 8u)  return dppf<0x128>(x);                // row_ror:8
    else if constexpr (M == 15u) return dppf<0x140>(x);                // row_mirror
    else if constexpr (M == 4u)  return dppf<0x141>(dppf<0x1B>(x));    // 7^3
    else if constexpr (M == 5u)  return dppf<0x141>(dppf<0x4E>(x));    // 7^2
    else if constexpr (M == 6u)  return dppf<0x141>(dppf<0xB1>(x));    // 7^1
    else if constexpr (M == 9u)  return dppf<0x128>(dppf<0xB1>(x));    // 8^1
    else if constexpr (M == 10u) return dppf<0x128>(dppf<0x4E>(x));    // 8^2
    else if constexpr (M == 11u) return dppf<0x128>(dppf<0x1B>(x));    // 8^3
    else if constexpr (M == 12u) return dppf<0x140>(dppf<0x1B>(x));    // 15^3
    else if constexpr (M == 13u) return dppf<0x140>(dppf<0x4E>(x));    // 15^2
    else                         return dppf<0x140>(dppf<0xB1>(x));    // 14 = 15^1
}

// Reduction folds for the epilogue: x + x^16 / x + x^32 (convention-independent)
__device__ __forceinline__ float redfold16(float x) {
#if __has_builtin(__builtin_amdgcn_permlane16_swap)
    u2v r = __builtin_amdgcn_permlane16_swap(__float_as_uint(x), __float_as_uint(x), false, false);
    return __uint_as_float(r[0]) + __uint_as_float(r[1]);
#else
    return x + __shfl_xor(x, 16);
#endif
}
__device__ __forceinline__ float redfold32(float x) {
#if __has_builtin(__builtin_amdgcn_permlane32_swap)
    u2v r = __builtin_amdgcn_permlane32_swap(__float_as_uint(x), __float_as_uint(x), false, false);
    return __uint_as_float(r[0]) + __uint_as_float(r[1]);
#else
    return x + __shfl_xor(x, 32);
#endif
}

// lane-xor by compile-time MASK.
// Policy (pipe balance): masks touching lane bits 4/5 -> DS pipe (ds_swizzle /
// ds_bpermute, 1 op/float); masks within a 16-lane row -> DPP on the VALU pipe.
template<unsigned M>
__device__ __forceinline__ float xlane(float x) {
    if constexpr (M == 0u) return x;
    else if constexpr ((M & 48u) != 0u) return __shfl_xor(x, (int)M);   // DS pipe
    else return dpplo<M>(x);                                            // VALU pipe
}

// ---- one single-qubit gate, interleaved-complex state, fully specialized --
template<int L, int K>
__device__ __forceinline__ void apply_gate(f2 (&st)[16],
                                           const float4 (*gm)[2], const int lane) {
    constexpr unsigned v  = TB.col[L][K];
    constexpr unsigned m  = TB.row[L][K];
    constexpr unsigned vl = v >> 4;
    constexpr int      vr = (int)(v & 15u);
    constexpr unsigned ml = m >> 4;
    constexpr int      mr = (int)(m & 15u);
    constexpr int      gi = L * NQ + K;

    int laneP = 0;
    if constexpr (ml != 0) laneP = __popc((unsigned)lane & ml) & 1;
    const float4 A = gm[gi][laneP];
    const f2 ocA = mk2(A.x, A.y), pcA = mk2(A.z, A.w);
    f2 ocB = ocA, pcB = pcA;
    if constexpr (mr != 0) {
        const float4 B = gm[gi][laneP ^ 1];
        ocB = mk2(B.x, B.y); pcB = mk2(B.z, B.w);
    }

    // partner values (all read before any write)
    f2 pv[16];
    #pragma unroll
    for (int r = 0; r < 16; ++r) {
        const f2 q = st[r ^ vr];
        if constexpr (vl == 0u) pv[r] = q;
        else pv[r] = mk2(xlane<vl>(q[0]), xlane<vl>(q[1]));
    }
    #pragma unroll
    for (int r = 0; r < 16; ++r) {
        const int pr = __builtin_popcount((unsigned)(r & mr)) & 1;  // compile-time folds
        const f2 oc = pr ? ocB : ocA;
        const f2 pc = pr ? pcB : pcA;
        f2 acc = mk2(0.f, 0.f);
        acc = cmac(acc, oc, st[r]);
        acc = cmac(acc, pc, pv[r]);
        st[r] = acc;
    }
}

__global__ __launch_bounds__(256, 4) void qrh_kernel(
    const float* __restrict__ theta, const float* __restrict__ rotw,
    const float* __restrict__ escale, const float* __restrict__ ebias,
    const float* __restrict__ W1, const float* __restrict__ b1,
    const float* __restrict__ W2, const float* __restrict__ b2,
    float* __restrict__ out)
{
    // per gate: group0 = [U00.re,U00.im,U01.re,U01.im], group1 = [U11.re,U11.im,U10.re,U10.im]
    __shared__ float4 gmat[4][NLAY * NQ][2];
    __shared__ float4 wtab[4][NQ];   // layer-0 product vectors: (a.re,a.im,b.re,b.im)

    const int tid  = threadIdx.x;
    const int lane = tid & 63;
    const int wv   = tid >> 6;
    const int b    = blockIdx.x * 4 + wv;

    // ---- per-gate 2x2 unitary, lane-parallel (lanes 0..39) ----
    if (lane < NLAY * NQ) {
        const int g = lane, l = g / NQ, k = g % NQ;
        const float th = theta[b * NQ + k];
        const int e2 = (l * NQ + k) * 2;
        const float t0 = escale[e2 + 0] * th + ebias[e2 + 0];
        const float t1 = escale[e2 + 1] * th + ebias[e2 + 1];
        float sn0, c0, sn1, c1;
        __sincosf(0.5f * t0, &sn0, &c0);
        __sincosf(0.5f * t1, &sn1, &c1);
        // U_enc = RX(t1) RZ(t0)
        const f2 E00 = mk2( c1 * c0,  -c1 * sn0);
        const f2 E01 = mk2( sn1 * sn0, -sn1 * c0);
        const f2 E10 = mk2(-sn1 * sn0, -sn1 * c0);
        const f2 E11 = mk2( c1 * c0,   c1 * sn0);
        const int r3 = (l * NQ + k) * 3;
        const float w0 = rotw[r3 + 0], w1 = rotw[r3 + 1], w2 = rotw[r3 + 2];
        float cw, sw, ca0, sa0, ca1, sa1;
        __sincosf(0.5f * w1, &sw, &cw);
        __sincosf(0.5f * (w0 + w2), &sa0, &ca0);
        __sincosf(0.5f * (w0 - w2), &sa1, &ca1);
        // U_rot = RZ(w2) RY(w1) RZ(w0)
        const f2 R00 = mk2( cw * ca0, -cw * sa0);
        const f2 R01 = mk2(-sw * ca1, -sw * sa1);
        const f2 R10 = mk2( sw * ca1, -sw * sa1);
        const f2 R11 = mk2( cw * ca0,  cw * sa0);
        auto cm = [](f2 a, f2 bb) { return mk2(a[0]*bb[0] - a[1]*bb[1], a[0]*bb[1] + a[1]*bb[0]); };
        const f2 U00 = cm(R00, E00) + cm(R01, E10);
        const f2 U01 = cm(R00, E01) + cm(R01, E11);
        const f2 U10 = cm(R10, E00) + cm(R11, E10);
        const f2 U11 = cm(R10, E01) + cm(R11, E11);
        gmat[wv][g][0] = make_float4(U00[0], U00[1], U01[0], U01[1]);
        gmat[wv][g][1] = make_float4(U11[0], U11[1], U10[0], U10[1]);
        if (l == 0) {
            // layer-0 acts on |+>^10: per-wire 2-vector w = U*(1,1)/sqrt(2)
            const float inv = 0.70710678118654752f;
            const f2 al = (U00 + U01) * inv;
            const f2 be = (U10 + U11) * inv;
            wtab[wv][k] = make_float4(al[0], al[1], be[0], be[1]);
        }
    }
    __syncthreads();

    // ---- layer-0 state = product state: amp(s) = prod_k w_k[s_k] ----------
    // storage s = (lane<<4) | r ; wires 0..5 <-> lane bits 5..0; wires 6..9 <-> r bits 3..0
    f2 st[16];
    {
        cpx pre;
        {
            const float4 q = wtab[wv][0];
            pre = ((lane >> 5) & 1) ? cpx{q.z, q.w} : cpx{q.x, q.y};
            #pragma unroll
            for (int k = 1; k < 6; ++k) {
                const float4 t = wtab[wv][k];
                const cpx w_ = ((lane >> (5 - k)) & 1) ? cpx{t.z, t.w} : cpx{t.x, t.y};
                pre = cxmul(pre, w_);
            }
        }
        const float4 q6 = wtab[wv][6], q7 = wtab[wv][7];
        const float4 q8 = wtab[wv][8], q9 = wtab[wv][9];
        const cpx w6[2] = {{q6.x, q6.y}, {q6.z, q6.w}};
        const cpx w7[2] = {{q7.x, q7.y}, {q7.z, q7.w}};
        const cpx w8[2] = {{q8.x, q8.y}, {q8.z, q8.w}};
        const cpx w9[2] = {{q9.x, q9.y}, {q9.z, q9.w}};
        cpx ph[4], tlo[4];
        #pragma unroll
        for (int a = 0; a < 4; ++a) {
            ph[a]  = cxmul(pre, cxmul(w6[a >> 1], w7[a & 1]));
            tlo[a] = cxmul(w8[a >> 1], w9[a & 1]);
        }
        #pragma unroll
        for (int r = 0; r < 16; ++r) {
            const cpx a0 = cxmul(ph[r >> 2], tlo[r & 3]);
            st[r] = mk2(a0.x, a0.y);
        }
    }

    const float4 (*gm)[2] = gmat[wv];

    #define GATE(L,K) apply_gate<L,K>(st, gm, lane);
    #define LAYER(L) GATE(L,0) GATE(L,1) GATE(L,2) GATE(L,3) GATE(L,4) \
                     GATE(L,5) GATE(L,6) GATE(L,7) GATE(L,8) GATE(L,9)
    LAYER(1)
    LAYER(2)
    LAYER(3)
    #undef LAYER
    #undef GATE

    // ---- measurement: probs then 4-bit FWHT over register index ----
    float w[16];
    #pragma unroll
    for (int r = 0; r < 16; ++r) {
        const f2 sq = st[r] * st[r];
        w[r] = sq[0] + sq[1];
    }
    #pragma unroll
    for (int bit = 1; bit < 16; bit <<= 1) {
        #pragma unroll
        for (int j = 0; j < 16; ++j) {
            if (!(j & bit)) {
                const float a = w[j], c = w[j | bit];
                w[j] = a + c; w[j | bit] = a - c;
            }
        }
    }
    // w[t] = sum_j (-1)^{popc(j&t)} p[j]

    float feats[NM];
    #pragma unroll
    for (int f = 0; f < NM; ++f) {
        const unsigned M = (f < NQ) ? TB.row[NLAY][f]
                                    : (TB.row[NLAY][f - NQ] ^ TB.row[NLAY][(f - NQ + 1) % NQ]);
        const int Ml = (int)(M >> 4), Mj = (int)(M & 15u);
        const float s = w[Mj];
        const int lsgn = __popc((unsigned)lane & (unsigned)Ml) & 1;
        feats[f] = lsgn ? -s : s;
    }
    // wave reduction over basis masks {1,2,7,8,16,32} (all VALU)
    #pragma unroll
    for (int f = 0; f < NM; ++f) {
        float v = feats[f];
        v += dppf<0xB1>(v);    // ^1
        v += dppf<0x4E>(v);    // ^2
        v += dppf<0x141>(v);   // ^7
        v += dppf<0x128>(v);   // ^8
        v = redfold16(v);
        v = redfold32(v);
        feats[f] = v;
    }

    // ---- MLP head: lanes 0..31 each one hidden unit ----
    float part = 0.f;
    if (lane < HID) {
        float acc = b1[lane];
        #pragma unroll
        for (int mm = 0; mm < NM; ++mm) acc = fmaf(feats[mm], W1[lane * NM + mm], acc);
        const float sg = 1.f / (1.f + __expf(-acc));
        part = acc * sg * W2[lane];
    }
    part += dppf<0xB1>(part);
    part += dppf<0x4E>(part);
    part += dppf<0x141>(part);
    part += dppf<0x128>(part);
    part = redfold16(part);
    part = redfold32(part);
    if (lane == 0) out[b] = part + b2[0];
}

extern "C" void kernel_launch(void* const* d_in, const int* in_sizes, int n_in,
                              void* d_out, int out_size, void* d_ws, size_t ws_size,
                              hipStream_t stream) {
    (void)in_sizes; (void)n_in; (void)out_size; (void)d_ws; (void)ws_size;
    const float* theta = (const float*)d_in[0];
    const float* rotw  = (const float*)d_in[1];
    const float* esc   = (const float*)d_in[2];
    const float* ebi   = (const float*)d_in[3];
    const float* W1    = (const float*)d_in[4];
    const float* b1    = (const float*)d_in[5];
    const float* W2    = (const float*)d_in[6];
    const float* b2    = (const float*)d_in[7];
    float* out = (float*)d_out;

    qrh_kernel<<<BATCH / 4, 256, 0, stream>>>(theta, rotw, esc, ebi, W1, b1, W2, b2, out);
}

// Round 9
// 96.763 us; speedup vs baseline: 1.1368x; 1.0011x over previous
//
#include <hip/hip_runtime.h>
#include <math.h>

#define NQ   10
#define NLAY 4
#define BATCH 4096
#define HID  32
#define NM   20   // 2*NQ

typedef float    f2  __attribute__((ext_vector_type(2)));
typedef unsigned u2v __attribute__((ext_vector_type(2)));

// ---------------------------------------------------------------------------
// Compile-time tracking of the CNOT ring as a GF(2) linear map.
// col[l][k] = pair-xor mask between storage indices for layer-l gate on wire k
// row[l][k] = parity mask giving logical bit x_k from storage index
// ---------------------------------------------------------------------------
struct Tables {
    unsigned col[NLAY + 1][NQ];
    unsigned row[NLAY + 1][NQ];
};

constexpr Tables make_tables() {
    Tables t{};
    unsigned col[NQ] = {}, row[NQ] = {};
    for (int k = 0; k < NQ; ++k) { col[k] = 1u << (NQ - 1 - k); row[k] = 1u << (NQ - 1 - k); }
    for (int l = 0; l <= NLAY; ++l) {
        for (int k = 0; k < NQ; ++k) { t.col[l][k] = col[k]; t.row[l][k] = row[k]; }
        for (int k = 0; k < NQ; ++k) {            // ring: CNOT(k, (k+1)%NQ)
            int c = k, tg = (k + 1) % NQ;
            col[c] ^= col[tg];
            row[tg] ^= row[c];
        }
    }
    return t;
}

static constexpr Tables TB = make_tables();

struct cpx { float x, y; };
__device__ __forceinline__ cpx cxmul(cpx a, cpx b) {
    return { fmaf(a.x, b.x, -a.y * b.y), fmaf(a.x, b.y, a.y * b.x) };
}

__device__ __forceinline__ f2 mk2(float a, float b) { f2 r; r[0] = a; r[1] = b; return r; }

// d = oc (*) s + pc (*) p   — complex MAC over interleaved (re,im) f2,
// forced to exactly 4 VOP3P instructions via op_sel/neg modifiers:
//   lo = oc0*s0 - oc1*s1 + pc0*p0 - pc1*p1
//   hi = oc0*s1 + oc1*s0 + pc0*p1 + pc1*p0
__device__ __forceinline__ f2 cpair_mac(f2 oc, f2 s, f2 pc, f2 p) {
    f2 t;
    asm("v_pk_mul_f32 %0, %1, %2 op_sel:[0,0] op_sel_hi:[0,1]"
        : "=v"(t) : "v"(oc), "v"(s));
    asm("v_pk_fma_f32 %0, %1, %2, %0 op_sel:[1,1,0] op_sel_hi:[1,0,1] neg_lo:[1,0,0]"
        : "+v"(t) : "v"(oc), "v"(s));
    asm("v_pk_fma_f32 %0, %1, %2, %0 op_sel:[0,0,0] op_sel_hi:[0,1,1]"
        : "+v"(t) : "v"(pc), "v"(p));
    asm("v_pk_fma_f32 %0, %1, %2, %0 op_sel:[1,1,0] op_sel_hi:[1,0,1] neg_lo:[1,0,0]"
        : "+v"(t) : "v"(pc), "v"(p));
    return t;
}

// ---- DPP lane-xor within a 16-lane row (VALU pipe) ------------------------
template<int CTRL>
__device__ __forceinline__ float dppf(float x) {
    return __int_as_float(__builtin_amdgcn_update_dpp(
        0, __float_as_int(x), CTRL, 0xF, 0xF, true));
}

template<unsigned M>
__device__ __forceinline__ float dpplo(float x) {
    static_assert(M < 16u, "dpplo handles masks 0..15");
    if constexpr (M == 0u)       return x;
    else if constexpr (M == 1u)  return dppf<0xB1>(x);                 // quad_perm [1,0,3,2]
    else if constexpr (M == 2u)  return dppf<0x4E>(x);                 // quad_perm [2,3,0,1]
    else if constexpr (M == 3u)  return dppf<0x1B>(x);                 // quad_perm [3,2,1,0]
    else if constexpr (M == 7u)  return dppf<0x141>(x);                // row_half_mirror
    else if constexpr (M == 8u)  return dppf<0x128>(x);                // row_ror:8
    else if constexpr (M == 15u) return dppf<0x140>(x);                // row_mirror
    else if constexpr (M == 4u)  return dppf<0x141>(dppf<0x1B>(x));    // 7^3
    else if constexpr (M == 5u)  return dppf<0x141>(dppf<0x4E>(x));    // 7^2
    else if constexpr (M == 6u)  return dppf<0x141>(dppf<0xB1>(x));    // 7^1
    else if constexpr (M == 9u)  return dppf<0x128>(dppf<0xB1>(x));    // 8^1
    else if constexpr (M == 10u) return dppf<0x128>(dppf<0x4E>(x));    // 8^2
    else if constexpr (M == 11u) return dppf<0x128>(dppf<0x1B>(x));    // 8^3
    else if constexpr (M == 12u) return dppf<0x140>(dppf<0x1B>(x));    // 15^3
    else if constexpr (M == 13u) return dppf<0x140>(dppf<0x4E>(x));    // 15^2
    else                         return dppf<0x140>(dppf<0xB1>(x));    // 14 = 15^1
}

// Reduction folds for the epilogue: x + x^16 / x + x^32 (convention-independent)
__device__ __forceinline__ float redfold16(float x) {
#if __has_builtin(__builtin_amdgcn_permlane16_swap)
    u2v r = __builtin_amdgcn_permlane16_swap(__float_as_uint(x), __float_as_uint(x), false, false);
    return __uint_as_float(r[0]) + __uint_as_float(r[1]);
#else
    return x + __shfl_xor(x, 16);
#endif
}
__device__ __forceinline__ float redfold32(float x) {
#if __has_builtin(__builtin_amdgcn_permlane32_swap)
    u2v r = __builtin_amdgcn_permlane32_swap(__float_as_uint(x), __float_as_uint(x), false, false);
    return __uint_as_float(r[0]) + __uint_as_float(r[1]);
#else
    return x + __shfl_xor(x, 32);
#endif
}

// lane-xor by compile-time MASK.
// Policy (pipe balance): masks touching lane bits 4/5 -> DS pipe (ds_bpermute,
// 1 op/float); masks within a 16-lane row -> DPP on the VALU pipe.
template<unsigned M>
__device__ __forceinline__ float xlane(float x) {
    if constexpr (M == 0u) return x;
    else if constexpr ((M & 48u) != 0u) return __shfl_xor(x, (int)M);   // DS pipe
    else return dpplo<M>(x);                                            // VALU pipe
}

// ---- one single-qubit gate, interleaved-complex state, fully specialized --
template<int L, int K>
__device__ __forceinline__ void apply_gate(f2 (&st)[16],
                                           const float4 (*gm)[2], const int lane) {
    constexpr unsigned v  = TB.col[L][K];
    constexpr unsigned m  = TB.row[L][K];
    constexpr unsigned vl = v >> 4;
    constexpr int      vr = (int)(v & 15u);
    constexpr unsigned ml = m >> 4;
    constexpr int      mr = (int)(m & 15u);
    constexpr int      gi = L * NQ + K;

    int laneP = 0;
    if constexpr (ml != 0) laneP = __popc((unsigned)lane & ml) & 1;
    const float4 A = gm[gi][laneP];
    const f2 ocA = mk2(A.x, A.y), pcA = mk2(A.z, A.w);
    f2 ocB = ocA, pcB = pcA;
    if constexpr (mr != 0) {
        const float4 B = gm[gi][laneP ^ 1];
        ocB = mk2(B.x, B.y); pcB = mk2(B.z, B.w);
    }

    // partner values (all read before any write)
    f2 pv[16];
    #pragma unroll
    for (int r = 0; r < 16; ++r) {
        const f2 q = st[r ^ vr];
        if constexpr (vl == 0u) pv[r] = q;
        else pv[r] = mk2(xlane<vl>(q[0]), xlane<vl>(q[1]));
    }
    #pragma unroll
    for (int r = 0; r < 16; ++r) {
        const int pr = __builtin_popcount((unsigned)(r & mr)) & 1;  // compile-time folds
        const f2 oc = pr ? ocB : ocA;
        const f2 pc = pr ? pcB : pcA;
        st[r] = cpair_mac(oc, st[r], pc, pv[r]);
    }
}

__global__ __launch_bounds__(256, 4) void qrh_kernel(
    const float* __restrict__ theta, const float* __restrict__ rotw,
    const float* __restrict__ escale, const float* __restrict__ ebias,
    const float* __restrict__ W1, const float* __restrict__ b1,
    const float* __restrict__ W2, const float* __restrict__ b2,
    float* __restrict__ out)
{
    // per gate: group0 = [U00.re,U00.im,U01.re,U01.im], group1 = [U11.re,U11.im,U10.re,U10.im]
    __shared__ float4 gmat[4][NLAY * NQ][2];
    __shared__ float4 wtab[4][NQ];   // layer-0 product vectors: (a.re,a.im,b.re,b.im)

    const int tid  = threadIdx.x;
    const int lane = tid & 63;
    const int wv   = tid >> 6;
    const int b    = blockIdx.x * 4 + wv;

    // ---- per-gate 2x2 unitary, lane-parallel (lanes 0..39) ----
    if (lane < NLAY * NQ) {
        const int g = lane, l = g / NQ, k = g % NQ;
        const float th = theta[b * NQ + k];
        const int e2 = (l * NQ + k) * 2;
        const float t0 = escale[e2 + 0] * th + ebias[e2 + 0];
        const float t1 = escale[e2 + 1] * th + ebias[e2 + 1];
        float sn0, c0, sn1, c1;
        __sincosf(0.5f * t0, &sn0, &c0);
        __sincosf(0.5f * t1, &sn1, &c1);
        // U_enc = RX(t1) RZ(t0)
        const f2 E00 = mk2( c1 * c0,  -c1 * sn0);
        const f2 E01 = mk2( sn1 * sn0, -sn1 * c0);
        const f2 E10 = mk2(-sn1 * sn0, -sn1 * c0);
        const f2 E11 = mk2( c1 * c0,   c1 * sn0);
        const int r3 = (l * NQ + k) * 3;
        const float w0 = rotw[r3 + 0], w1 = rotw[r3 + 1], w2 = rotw[r3 + 2];
        float cw, sw, ca0, sa0, ca1, sa1;
        __sincosf(0.5f * w1, &sw, &cw);
        __sincosf(0.5f * (w0 + w2), &sa0, &ca0);
        __sincosf(0.5f * (w0 - w2), &sa1, &ca1);
        // U_rot = RZ(w2) RY(w1) RZ(w0)
        const f2 R00 = mk2( cw * ca0, -cw * sa0);
        const f2 R01 = mk2(-sw * ca1, -sw * sa1);
        const f2 R10 = mk2( sw * ca1, -sw * sa1);
        const f2 R11 = mk2( cw * ca0,  cw * sa0);
        auto cm = [](f2 a, f2 bb) { return mk2(a[0]*bb[0] - a[1]*bb[1], a[0]*bb[1] + a[1]*bb[0]); };
        const f2 U00 = cm(R00, E00) + cm(R01, E10);
        const f2 U01 = cm(R00, E01) + cm(R01, E11);
        const f2 U10 = cm(R10, E00) + cm(R11, E10);
        const f2 U11 = cm(R10, E01) + cm(R11, E11);
        gmat[wv][g][0] = make_float4(U00[0], U00[1], U01[0], U01[1]);
        gmat[wv][g][1] = make_float4(U11[0], U11[1], U10[0], U10[1]);
        if (l == 0) {
            // layer-0 acts on |+>^10: per-wire 2-vector w = U*(1,1)/sqrt(2)
            const float inv = 0.70710678118654752f;
            const f2 al = (U00 + U01) * inv;
            const f2 be = (U10 + U11) * inv;
            wtab[wv][k] = make_float4(al[0], al[1], be[0], be[1]);
        }
    }
    __syncthreads();

    // ---- layer-0 state = product state: amp(s) = prod_k w_k[s_k] ----------
    // storage s = (lane<<4) | r ; wires 0..5 <-> lane bits 5..0; wires 6..9 <-> r bits 3..0
    f2 st[16];
    {
        cpx pre;
        {
            const float4 q = wtab[wv][0];
            pre = ((lane >> 5) & 1) ? cpx{q.z, q.w} : cpx{q.x, q.y};
            #pragma unroll
            for (int k = 1; k < 6; ++k) {
                const float4 t = wtab[wv][k];
                const cpx w_ = ((lane >> (5 - k)) & 1) ? cpx{t.z, t.w} : cpx{t.x, t.y};
                pre = cxmul(pre, w_);
            }
        }
        const float4 q6 = wtab[wv][6], q7 = wtab[wv][7];
        const float4 q8 = wtab[wv][8], q9 = wtab[wv][9];
        const cpx w6[2] = {{q6.x, q6.y}, {q6.z, q6.w}};
        const cpx w7[2] = {{q7.x, q7.y}, {q7.z, q7.w}};
        const cpx w8[2] = {{q8.x, q8.y}, {q8.z, q8.w}};
        const cpx w9[2] = {{q9.x, q9.y}, {q9.z, q9.w}};
        cpx ph[4], tlo[4];
        #pragma unroll
        for (int a = 0; a < 4; ++a) {
            ph[a]  = cxmul(pre, cxmul(w6[a >> 1], w7[a & 1]));
            tlo[a] = cxmul(w8[a >> 1], w9[a & 1]);
        }
        #pragma unroll
        for (int r = 0; r < 16; ++r) {
            const cpx a0 = cxmul(ph[r >> 2], tlo[r & 3]);
            st[r] = mk2(a0.x, a0.y);
        }
    }

    const float4 (*gm)[2] = gmat[wv];

    #define GATE(L,K) apply_gate<L,K>(st, gm, lane);
    #define LAYER(L) GATE(L,0) GATE(L,1) GATE(L,2) GATE(L,3) GATE(L,4) \
                     GATE(L,5) GATE(L,6) GATE(L,7) GATE(L,8) GATE(L,9)
    LAYER(1)
    LAYER(2)
    LAYER(3)
    #undef LAYER
    #undef GATE

    // ---- measurement: probs then 4-bit FWHT over register index ----
    float w[16];
    #pragma unroll
    for (int r = 0; r < 16; ++r) {
        const f2 sq = st[r] * st[r];
        w[r] = sq[0] + sq[1];
    }
    #pragma unroll
    for (int bit = 1; bit < 16; bit <<= 1) {
        #pragma unroll
        for (int j = 0; j < 16; ++j) {
            if (!(j & bit)) {
                const float a = w[j], c = w[j | bit];
                w[j] = a + c; w[j | bit] = a - c;
            }
        }
    }
    // w[t] = sum_j (-1)^{popc(j&t)} p[j]

    float feats[NM];
    #pragma unroll
    for (int f = 0; f < NM; ++f) {
        const unsigned M = (f < NQ) ? TB.row[NLAY][f]
                                    : (TB.row[NLAY][f - NQ] ^ TB.row[NLAY][(f - NQ + 1) % NQ]);
        const int Ml = (int)(M >> 4), Mj = (int)(M & 15u);
        const float s = w[Mj];
        const int lsgn = __popc((unsigned)lane & (unsigned)Ml) & 1;
        feats[f] = lsgn ? -s : s;
    }
    // wave reduction over basis masks {1,2,7,8,16,32} (all VALU)
    #pragma unroll
    for (int f = 0; f < NM; ++f) {
        float v = feats[f];
        v += dppf<0xB1>(v);    // ^1
        v += dppf<0x4E>(v);    // ^2
        v += dppf<0x141>(v);   // ^7
        v += dppf<0x128>(v);   // ^8
        v = redfold16(v);
        v = redfold32(v);
        feats[f] = v;
    }

    // ---- MLP head: lanes 0..31 each one hidden unit ----
    float part = 0.f;
    if (lane < HID) {
        float acc = b1[lane];
        #pragma unroll
        for (int mm = 0; mm < NM; ++mm) acc = fmaf(feats[mm], W1[lane * NM + mm], acc);
        const float sg = 1.f / (1.f + __expf(-acc));
        part = acc * sg * W2[lane];
    }
    part += dppf<0xB1>(part);
    part += dppf<0x4E>(part);
    part += dppf<0x141>(part);
    part += dppf<0x128>(part);
    part = redfold16(part);
    part = redfold32(part);
    if (lane == 0) out[b] = part + b2[0];
}

extern "C" void kernel_launch(void* const* d_in, const int* in_sizes, int n_in,
                              void* d_out, int out_size, void* d_ws, size_t ws_size,
                              hipStream_t stream) {
    (void)in_sizes; (void)n_in; (void)out_size; (void)d_ws; (void)ws_size;
    const float* theta = (const float*)d_in[0];
    const float* rotw  = (const float*)d_in[1];
    const float* esc   = (const float*)d_in[2];
    const float* ebi   = (const float*)d_in[3];
    const float* W1    = (const float*)d_in[4];
    const float* b1    = (const float*)d_in[5];
    const float* W2    = (const float*)d_in[6];
    const float* b2    = (const float*)d_in[7];
    float* out = (float*)d_out;

    qrh_kernel<<<BATCH / 4, 256, 0, stream>>>(theta, rotw, esc, ebi, W1, b1, W2, b2, out);
}